// Round 9
// baseline (315.302 us; speedup 1.0000x reference)
//
#include <hip/hip_runtime.h>

#define NB 4
#define NC 512
#define NT 4096
#define NTILE 528   // 32*33/2 triangular 128x128 tiles per batch

typedef __attribute__((ext_vector_type(4))) float f32x4;
typedef __attribute__((ext_vector_type(8))) short short8;

typedef const __attribute__((address_space(1))) unsigned int* gp1_t;
typedef __attribute__((address_space(3))) unsigned int* lp3_t;

__device__ __forceinline__ void gload16(const short* g, short* l) {
  // async global->LDS, 16B/lane; LDS dest = wave-uniform base + lane*16
  __builtin_amdgcn_global_load_lds((gp1_t)g, (lp3_t)l, 16, 0, 0);
}

// HW fp32 global atomic add (device scope). Fallback to atomicAdd if the
// builtin is unavailable; contention here is <=4 writers per element.
__device__ __forceinline__ void atom_add_f32(float* p, float v) {
#if __has_builtin(__builtin_amdgcn_global_atomic_fadd_f32)
  typedef __attribute__((address_space(1))) float gfloat;
  __builtin_amdgcn_global_atomic_fadd_f32((gfloat*)p, v);
#else
  atomicAdd(p, v);
#endif
}

// Raw barrier / waitcnt with memory clobbers: keeps the compiler from
// draining vmcnt(0) at every barrier. Each wave issues 4 DMAs per k-step;
// with depth-2 prefetch up to 12 can be outstanding. vmcnt(8) = the oldest
// step's 4 have landed; vmcnt(4) = second-newest landed.
#define BARRIER() asm volatile("s_barrier" ::: "memory")
#define WAITVM0() asm volatile("s_waitcnt vmcnt(0)" ::: "memory")
#define WAITVM4() asm volatile("s_waitcnt vmcnt(4)" ::: "memory")
#define WAITVM8() asm volatile("s_waitcnt vmcnt(8)" ::: "memory")

__device__ __forceinline__ short f2bf(float f) {
  union { float f; unsigned u; } v; v.f = f;
  unsigned r = v.u + 0x7fffu + ((v.u >> 16) & 1u);
  return (short)(r >> 16);
}
__device__ __forceinline__ float bf2f(short s) {
  union { unsigned u; float f; } v; v.u = ((unsigned)(unsigned short)s) << 16;
  return v.f;
}

// ---------------------------------------------------------------------------
// Triple-buffered NT-GEMM core, prefetch depth 2: D[m,n] += sum_k A[m,k]*B[n,k]
// 128x128 tile, BK=32, 4 waves, 4x4 of 16x16x32 bf16 MFMAs per wave.
// lds: 24576 shorts (48 KB), buffer b at lds + b*8192 (A 4096 + B 4096).
// ---------------------------------------------------------------------------
__device__ __forceinline__ void gemm_tile(const short* __restrict__ A, int lda,
                                          const short* __restrict__ Bg, int ldb,
                                          int m0, int n0, int ksteps,
                                          f32x4 (&acc)[4][4], short* lds) {
  const int tid  = threadIdx.x;
  const int lane = tid & 63;
  const int wv   = tid >> 6;
  const int wm = (wv >> 1) * 64;
  const int wn = (wv & 1) * 64;
  const int srow = wv * 16 + (lane >> 2);   // staging row, 0..63 (+64 issue 1)
  const int scol = (lane & 3) * 8;          // staging col offset in shorts
  const int fm  = lane & 15;                // fragment row
  const int fko = (lane >> 4) * 8;          // fragment k offset in shorts

  const short* Ap0 = A  + (size_t)(m0 + srow) * lda + scol;
  const short* Ap1 = Ap0 + (size_t)64 * lda;
  const short* Bp0 = Bg + (size_t)(n0 + srow) * ldb + scol;
  const short* Bp1 = Bp0 + (size_t)64 * ldb;

  auto issue = [&](int kt) {
    short* base = lds + (kt % 3) * 8192;
    const int k0 = kt * 32;
    gload16(Ap0 + k0, base + wv * 512);
    gload16(Ap1 + k0, base + 2048 + wv * 512);
    gload16(Bp0 + k0, base + 4096 + wv * 512);
    gload16(Bp1 + k0, base + 6144 + wv * 512);
  };

  issue(0);
  if (ksteps > 1) issue(1);
  for (int kt = 0; kt < ksteps; ++kt) {
    const short* As = lds + (kt % 3) * 8192;
    const short* Bs = As + 4096;
    if (kt) BARRIER();                      // buf (kt+2)%3's readers done
    if (kt + 2 < ksteps)      { issue(kt + 2); WAITVM8(); }
    else if (kt + 1 < ksteps) { WAITVM4(); }
    else                      { WAITVM0(); }
    BARRIER();                              // all waves' step-kt DMAs landed
    short8 af[4], bfr[4];
#pragma unroll
    for (int i = 0; i < 4; ++i)
      af[i] = *(const short8*)(As + (wm + i * 16 + fm) * 32 + fko);
#pragma unroll
    for (int j = 0; j < 4; ++j)
      bfr[j] = *(const short8*)(Bs + (wn + j * 16 + fm) * 32 + fko);
#pragma unroll
    for (int i = 0; i < 4; ++i)
#pragma unroll
      for (int j = 0; j < 4; ++j)
        acc[i][j] = __builtin_amdgcn_mfma_f32_16x16x32_bf16(af[i], bfr[j], acc[i][j], 0, 0, 0);
  }
}

#define ACC_INIT                                  \
  f32x4 acc[4][4];                                \
  {                                               \
    const f32x4 z = {0.f, 0.f, 0.f, 0.f};         \
    for (int i = 0; i < 4; ++i)                   \
      for (int j = 0; j < 4; ++j) acc[i][j] = z;  \
  }

#define EPI_IDX                                   \
  const int lane = threadIdx.x & 63;              \
  const int wave = threadIdx.x >> 6;              \
  const int wm = (wave >> 1) * 64;                \
  const int wn = (wave & 1) * 64;

#define GEMM_LDS __shared__ short lds[24576];

// ---------------------------------------------------------------------------
// XCD-locality swizzle for flat grids of (row-stripe, 4 col-chunks):
// dispatch round-robins blockIdx.x%8 across XCDs; decode so each XCD sees 4
// consecutive col-chunks of the same row-stripe. rows descend (long first).
// ---------------------------------------------------------------------------
__device__ __forceinline__ void xcd_rowchunk(int x, int nrows, int& row, int& chunk) {
  const int xcd  = x & 7;
  const int slot = x >> 3;
  row   = nrows - 1 - (xcd + 8 * (slot >> 2));
  chunk = slot & 3;
}

// ---------------------------------------------------------------------------
// x [B,C,T] f32 -> xT [B,T,C] bf16 (tiled transpose through LDS)
// ---------------------------------------------------------------------------
__global__ __launch_bounds__(256) void k_transpose(const float* __restrict__ x,
                                                   short* __restrict__ xT) {
  __shared__ float tile[32][33];
  const int b  = blockIdx.z;
  const int t0 = blockIdx.x * 32;
  const int c0 = blockIdx.y * 32;
  const int tx = threadIdx.x & 31;
  const int ty = threadIdx.x >> 5;
  const float* xp = x + ((size_t)b * NC + c0) * NT + t0;
#pragma unroll
  for (int i = 0; i < 32; i += 8)
    tile[ty + i][tx] = xp[(size_t)(ty + i) * NT + tx];
  __syncthreads();
  short* op = xT + ((size_t)b * NT + t0) * NC + c0;
#pragma unroll
  for (int i = 0; i < 32; i += 8)
    op[(size_t)(ty + i) * NC + tx] = f2bf(tile[tx][ty + i]);
}

// f32 -> bf16 conversion of all 4 weight matrices in one launch
__global__ __launch_bounds__(256) void k_wcvt(const float* __restrict__ s0, const float* __restrict__ s1,
                                              const float* __restrict__ s2, const float* __restrict__ s3,
                                              short* __restrict__ d0, short* __restrict__ d1,
                                              short* __restrict__ d2, short* __restrict__ d3) {
  const float* s; short* d;
  switch (blockIdx.y) {
    case 0: s = s0; d = d0; break;
    case 1: s = s1; d = d1; break;
    case 2: s = s2; d = d2; break;
    default: s = s3; d = d3; break;
  }
  const int i = (blockIdx.x * 256 + threadIdx.x) * 4;
  const float4 v = *(const float4*)(s + i);
  short4 o;
  o.x = f2bf(v.x); o.y = f2bf(v.y); o.z = f2bf(v.z); o.w = f2bf(v.w);
  *(short4*)(d + i) = o;
}

// ---------------------------------------------------------------------------
// Fused Q/K/V projections, one launch. blockIdx.y selects:
//   y=0: Q[t,o] = xT·Wq^T + bq   -> bf16 [T,C]
//   y=1: K[t,o] = xT·Wk^T + bk   -> bf16 [T,C]
//   y=2: VT[o,t] = Wv·xT^T + bv  -> bf16 [C,T]
// flat x-grid (128): XCD-grouped row-stripe of xT serves 4 chunks.
// ---------------------------------------------------------------------------
__global__ __launch_bounds__(256, 3) void k_qkv(const short* __restrict__ xT,
                                                const short* __restrict__ Wq,
                                                const float* __restrict__ bq,
                                                const short* __restrict__ Wk,
                                                const float* __restrict__ bk,
                                                const short* __restrict__ Wv,
                                                const float* __restrict__ bv,
                                                short* __restrict__ Q,
                                                short* __restrict__ K,
                                                short* __restrict__ VT) {
  GEMM_LDS;
  const int b = blockIdx.z;
  const int y = blockIdx.y;
  int row, chunk;
  xcd_rowchunk((int)blockIdx.x, NT / 128, row, chunk);
  const short* Xb = xT + (size_t)b * NT * NC;
  ACC_INIT;
  if (y < 2) {
    const short* W = (y == 0) ? Wq : Wk;
    const float* bias = (y == 0) ? bq : bk;
    short* O = ((y == 0) ? Q : K) + (size_t)b * NT * NC;
    const int m0 = row * 128;
    const int n0 = chunk * 128;
    gemm_tile(Xb, NC, W, NC, m0, n0, NC / 32, acc, lds);
    EPI_IDX;
#pragma unroll
    for (int j = 0; j < 4; ++j) {
      const int n = n0 + wn + j * 16 + (lane & 15);
      const float bv_ = bias[n];
#pragma unroll
      for (int i = 0; i < 4; ++i) {
        const int mb = m0 + wm + i * 16 + ((lane >> 4) * 4);
#pragma unroll
        for (int r = 0; r < 4; ++r)
          O[(size_t)(mb + r) * NC + n] = f2bf(acc[i][j][r] + bv_);
      }
    }
  } else {
    const int n0 = row * 128;    // xT row-stripe (B operand)
    const int m0 = chunk * 128;  // Wv row chunk
    gemm_tile(Wv, NC, Xb, NC, m0, n0, NC / 32, acc, lds);
    EPI_IDX;
    short* O = VT + (size_t)b * NC * NT;
#pragma unroll
    for (int j = 0; j < 4; ++j) {
      const int n = n0 + wn + j * 16 + (lane & 15);
#pragma unroll
      for (int i = 0; i < 4; ++i) {
        const int mb = m0 + wm + i * 16 + ((lane >> 4) * 4);
#pragma unroll
        for (int r = 0; r < 4; ++r)
          O[(size_t)(mb + r) * NT + n] = f2bf(acc[i][j][r] + bv[mb + r]);
      }
    }
  }
}

// ---------------------------------------------------------------------------
// Scores + softmax numerator into TRIANGULAR-PACKED tile layout.
// XCD-locality: 8x8-tile supertile decomposition; block x -> (xcd=x&7,
// slot=x>>3) gives each XCD a contiguous 66-tile range (~2 MB working set).
// P = exp(scale*q.k) for s<=t else 0, contiguous 128x128 bf16 tile at
// bm*(bm+1)/2+bn. Interior tiles (bn<bm) take a branchless epilogue; only
// the 32 diagonal tiles evaluate the causal compare.
// ---------------------------------------------------------------------------
__global__ __launch_bounds__(256, 3) void k_scores(const short* __restrict__ Q,
                                                   const short* __restrict__ K,
                                                   short* __restrict__ P,
                                                   float* __restrict__ Lrow) {
  // supertile-ordered position, contiguous per XCD
  const int p = (((int)blockIdx.x & 7) * 66) + ((int)blockIdx.x >> 3);
  int bm = 0, bn = 0;
  {
    int base = 0;
    for (int sr = 0; sr < 4; ++sr) {
      bool done = false;
      for (int sc = 0; sc <= sr; ++sc) {
        const int sz = (sc == sr) ? 36 : 64;
        if (p < base + sz) {
          const int q = p - base;
          int i, j;
          if (sc == sr) {
            i = 0;
            while ((i + 1) * (i + 2) / 2 <= q) ++i;
            j = q - i * (i + 1) / 2;
          } else { i = q >> 3; j = q & 7; }
          bm = sr * 8 + i; bn = sc * 8 + j;
          done = true; break;
        }
        base += sz;
      }
      if (done) break;
    }
  }
  GEMM_LDS;
  const int b  = blockIdx.z;
  const int m0 = bm * 128;
  const int n0 = bn * 128;
  ACC_INIT;
  gemm_tile(Q + (size_t)b * NT * NC, NC, K + (size_t)b * NT * NC, NC,
            m0, n0, NC / 32, acc, lds);
  EPI_IDX;
  const float scale = 0.04419417382415922f;  // 512^-0.5
  const int idx = bm * (bm + 1) / 2 + bn;    // storage order unchanged
  short* Tp = P + ((size_t)b * NTILE + (size_t)idx) * 16384;
  float* Lp = Lrow + (size_t)b * NT;
  float psum[4][4];
#pragma unroll
  for (int i = 0; i < 4; ++i)
#pragma unroll
    for (int r = 0; r < 4; ++r) psum[i][r] = 0.f;

  if (bn < bm) {
    // interior: causal mask always true -- branchless
#pragma unroll
    for (int j = 0; j < 4; ++j) {
      const int ln = wn + j * 16 + (lane & 15);
#pragma unroll
      for (int i = 0; i < 4; ++i) {
        const int lmb = wm + i * 16 + ((lane >> 4) * 4);
#pragma unroll
        for (int r = 0; r < 4; ++r) {
          const short pb = f2bf(__expf(acc[i][j][r] * scale));
          Tp[(lmb + r) * 128 + ln] = pb;
          psum[i][r] += bf2f(pb);       // L accumulates exactly what P stores
        }
      }
    }
  } else {
    // diagonal tile: evaluate mask per element
#pragma unroll
    for (int j = 0; j < 4; ++j) {
      const int ln = wn + j * 16 + (lane & 15);
      const int n  = n0 + ln;
#pragma unroll
      for (int i = 0; i < 4; ++i) {
        const int lmb = wm + i * 16 + ((lane >> 4) * 4);
#pragma unroll
        for (int r = 0; r < 4; ++r) {
          const int m = m0 + lmb + r;
          float pr = 0.f;
          short pb = 0;
          if (n <= m) {
            pb = f2bf(__expf(acc[i][j][r] * scale));
            pr = bf2f(pb);
          }
          Tp[(lmb + r) * 128 + ln] = pb;
          psum[i][r] += pr;
        }
      }
    }
  }
#pragma unroll
  for (int i = 0; i < 4; ++i)
#pragma unroll
    for (int r = 0; r < 4; ++r) {
      float v = psum[i][r];
      v += __shfl_xor(v, 1);
      v += __shfl_xor(v, 2);
      v += __shfl_xor(v, 4);
      v += __shfl_xor(v, 8);
      if ((lane & 15) == 0) {
        const int m = m0 + wm + i * 16 + ((lane >> 4) * 4) + r;
        atomicAdd(&Lp[m], v);
      }
    }
}

// ---------------------------------------------------------------------------
// PV split-K: each block computes a <=8-tile s-segment of one (bm,chunk)
// output tile and atomically accumulates the fp32 partial into Hacc[T,C].
// 80 segments per chunk (rows bm: ceil((bm+1)/8) segs), 4 chunks -> 320
// blocks per batch, every block <=32 k-steps (kills the bm=31 critical path).
// Scheduling: xcd=x&7, slot=x>>3; chunk=slot&3 keeps the 4 chunks of a
// segment on one XCD (P fetched once); p=(slot>>2)*8+xcd round-robins the
// longest-first segment list across XCDs for balance.
// ---------------------------------------------------------------------------
__global__ __launch_bounds__(256, 3) void k_pv(const short* __restrict__ P,
                                               const short* __restrict__ VT,
                                               float* __restrict__ Hacc) {
  GEMM_LDS;
  const int b = blockIdx.z;
  const int x = (int)blockIdx.x;
  const int xcd  = x & 7;
  const int slot = x >> 3;           // 0..39
  const int chunk = slot & 3;
  const int p = ((slot >> 2) << 3) + xcd;   // segment id 0..79, longest first
  int bm = 31, s = 0;
  {
    int accum = 0;
    for (int r = 31; r >= 0; --r) {
      const int ns = (r + 8) >> 3;   // ceil((r+1)/8)
      if (p < accum + ns) { bm = r; s = p - accum; break; }
      accum += ns;
    }
  }
  const int tc = min(8, bm + 1 - s * 8);  // tiles in this segment
  const int ksteps = tc * 4;
  const int m0 = bm * 128;
  const int n0 = chunk * 128;
  const int gbase = s * 32;               // global k-step offset

  const short* Ptri = P + ((size_t)b * NTILE + (size_t)bm * (bm + 1) / 2) * 16384;
  const short* Bg   = VT + (size_t)b * NC * NT;

  ACC_INIT;
  const int tid  = threadIdx.x;
  const int lane = tid & 63;
  const int wv   = tid >> 6;
  const int wm = (wv >> 1) * 64;
  const int wn = (wv & 1) * 64;
  const int srow = wv * 16 + (lane >> 2);
  const int scol = (lane & 3) * 8;
  const int fm  = lane & 15;
  const int fko = (lane >> 4) * 8;

  const short* Bp0 = Bg + (size_t)(n0 + srow) * NT + scol;
  const short* Bp1 = Bp0 + (size_t)64 * NT;

  auto issue = [&](int kt) {
    short* base = lds + (kt % 3) * 8192;
    const int g = gbase + kt;
    const short* At = Ptri + (size_t)(g >> 2) * 16384 + (g & 3) * 32;
    const short* Ap0 = At + srow * 128 + scol;
    gload16(Ap0, base + wv * 512);
    gload16(Ap0 + 64 * 128, base + 2048 + wv * 512);
    gload16(Bp0 + g * 32, base + 4096 + wv * 512);
    gload16(Bp1 + g * 32, base + 6144 + wv * 512);
  };

  issue(0);
  if (ksteps > 1) issue(1);
  for (int kt = 0; kt < ksteps; ++kt) {
    const short* As = lds + (kt % 3) * 8192;
    const short* Bs = As + 4096;
    if (kt) BARRIER();
    if (kt + 2 < ksteps)      { issue(kt + 2); WAITVM8(); }
    else if (kt + 1 < ksteps) { WAITVM4(); }
    else                      { WAITVM0(); }
    BARRIER();
    short8 af[4], bfr[4];
#pragma unroll
    for (int i = 0; i < 4; ++i)
      af[i] = *(const short8*)(As + (wm + i * 16 + fm) * 32 + fko);
#pragma unroll
    for (int j = 0; j < 4; ++j)
      bfr[j] = *(const short8*)(Bs + (wn + j * 16 + fm) * 32 + fko);
#pragma unroll
    for (int i = 0; i < 4; ++i)
#pragma unroll
      for (int j = 0; j < 4; ++j)
        acc[i][j] = __builtin_amdgcn_mfma_f32_16x16x32_bf16(af[i], bfr[j], acc[i][j], 0, 0, 0);
  }

  float* Ha = Hacc + (size_t)b * NT * NC;
#pragma unroll
  for (int i = 0; i < 4; ++i) {
    const int mb = m0 + wm + i * 16 + ((lane >> 4) * 4);
#pragma unroll
    for (int j = 0; j < 4; ++j) {
      const int n = n0 + wn + j * 16 + (lane & 15);
#pragma unroll
      for (int r = 0; r < 4; ++r)
        atom_add_f32(&Ha[(size_t)(mb + r) * NC + n], acc[i][j][r]);
    }
  }
}

// ---------------------------------------------------------------------------
// H finalize: Hb[t,c] = bf16(Hacc[t,c] / L[t]). 2 rows per block.
// ---------------------------------------------------------------------------
__global__ __launch_bounds__(256) void k_hcvt(const float* __restrict__ Hacc,
                                              const float* __restrict__ Lr,
                                              short* __restrict__ H) {
  const int tid = threadIdx.x;
  const int row = (int)blockIdx.x * 2 + (tid >> 7);   // 0..NB*NT-1
  const int col = (tid & 127) * 4;
  const float rinv = 1.f / Lr[row];
  const float4 v = *(const float4*)(Hacc + (size_t)row * NC + col);
  short4 o;
  o.x = f2bf(v.x * rinv); o.y = f2bf(v.y * rinv);
  o.z = f2bf(v.z * rinv); o.w = f2bf(v.w * rinv);
  *(short4*)(H + (size_t)row * NC + col) = o;
}

// ---------------------------------------------------------------------------
// Output projection + residual: out[o,t] = Wp·H^T + bp[o] + x[o,t], fp32.
// flat grid (128, 1, B): XCD-grouped so one H row-stripe serves 4 m0 chunks.
// ---------------------------------------------------------------------------
__global__ __launch_bounds__(256, 3) void k_out(const short* __restrict__ W,
                                                const short* __restrict__ H,
                                                const float* __restrict__ bias,
                                                const float* __restrict__ x,
                                                float* __restrict__ out) {
  GEMM_LDS;
  const int b = blockIdx.z;
  int row, chunk;
  xcd_rowchunk((int)blockIdx.x, NT / 128, row, chunk);
  const int n0 = row * 128;    // H row-stripe (B operand)
  const int m0 = chunk * 128;  // Wp row chunk
  ACC_INIT;
  gemm_tile(W, NC, H + (size_t)b * NT * NC, NC, m0, n0, NC / 32, acc, lds);
  EPI_IDX;
#pragma unroll
  for (int j = 0; j < 4; ++j) {
    const int n = n0 + wn + j * 16 + (lane & 15);
#pragma unroll
    for (int i = 0; i < 4; ++i) {
      const int mb = m0 + wm + i * 16 + ((lane >> 4) * 4);
#pragma unroll
      for (int r = 0; r < 4; ++r) {
        const int m = mb + r;
        const size_t idx = ((size_t)b * NC + m) * NT + n;
        out[idx] = acc[i][j][r] + bias[m] + x[idx];
      }
    }
  }
}

// ---------------------------------------------------------------------------
extern "C" void kernel_launch(void* const* d_in, const int* in_sizes, int n_in,
                              void* d_out, int out_size, void* d_ws, size_t ws_size,
                              hipStream_t stream) {
  (void)in_sizes; (void)n_in; (void)out_size; (void)ws_size;
  const float* x  = (const float*)d_in[0];
  const float* Wq = (const float*)d_in[1];
  const float* bq = (const float*)d_in[2];
  const float* Wk = (const float*)d_in[3];
  const float* bk = (const float*)d_in[4];
  const float* Wv = (const float*)d_in[5];
  const float* bv = (const float*)d_in[6];
  const float* Wp = (const float*)d_in[7];
  const float* bp = (const float*)d_in[8];
  float* out = (float*)d_out;

  char* ws = (char*)d_ws;
  size_t off = 0;
  auto alloc = [&](size_t bytes) { char* p = ws + off; off += bytes; return p; };
  short* xT  = (short*)alloc((size_t)NB * NT * NC * 2);
  short* Qb  = (short*)alloc((size_t)NB * NT * NC * 2);
  short* Kb  = (short*)alloc((size_t)NB * NT * NC * 2);
  short* VTb = (short*)alloc((size_t)NB * NC * NT * 2);
  short* Hb  = (short*)alloc((size_t)NB * NT * NC * 2);
  float* Hacc = (float*)alloc((size_t)NB * NT * NC * 4);  // fp32 split-K acc
  short* Wqb = (short*)alloc((size_t)NC * NC * 2);
  short* Wkb = (short*)alloc((size_t)NC * NC * 2);
  short* Wvb = (short*)alloc((size_t)NC * NC * 2);
  short* Wpb = (short*)alloc((size_t)NC * NC * 2);
  float* Lr  = (float*)alloc((size_t)NB * NT * 4);
  short* Pb  = (short*)alloc((size_t)NB * NTILE * 16384 * 2);  // 69 MB packed

  hipMemsetAsync(Lr, 0, (size_t)NB * NT * 4, stream);
  hipMemsetAsync(Hacc, 0, (size_t)NB * NT * NC * 4, stream);

  const dim3 blk(256);
  k_wcvt<<<dim3(NC * NC / 1024, 4), blk, 0, stream>>>(Wq, Wk, Wv, Wp, Wqb, Wkb, Wvb, Wpb);

  k_transpose<<<dim3(NT / 32, NC / 32, NB), blk, 0, stream>>>(x, xT);

  k_qkv<<<dim3(128, 3, NB), blk, 0, stream>>>(xT, Wqb, bq, Wkb, bk, Wvb, bv, Qb, Kb, VTb);

  k_scores<<<dim3(NTILE, 1, NB), blk, 0, stream>>>(Qb, Kb, Pb, Lr);
  k_pv<<<dim3(320, 1, NB), blk, 0, stream>>>(Pb, VTb, Hacc);
  k_hcvt<<<dim3(NB * NT / 2), blk, 0, stream>>>(Hacc, Lr, Hb);
  k_out<<<dim3(128, 1, NB), blk, 0, stream>>>(Wpb, Hb, bp, x, out);
}